// Round 9
// baseline (247.549 us; speedup 1.0000x reference)
//
#include <hip/hip_runtime.h>

typedef __attribute__((ext_vector_type(8))) short bf16x8;
typedef __attribute__((ext_vector_type(4))) float f32x4;

static constexpr int INC = 64, HIDC = 128, OUTC = 64;
static constexpr int NPART = 8;     // dst partitions == XCDs (bid%8 -> XCD round-robin)
static constexpr int NSLICE = 128;  // edge slices per partition
static constexpr int CAP = 64;      // max degree bucket (Poisson(16): P(>=64)~3e-22)

__device__ __forceinline__ unsigned short f2bf(float f) {
    union { float f; unsigned u; } v; v.f = f;
    unsigned r = v.u + 0x7FFFu + ((v.u >> 16) & 1u);   // round-to-nearest-even
    return (unsigned short)(r >> 16);
}
__device__ __forceinline__ float bf2f(unsigned short h) {
    union { unsigned u; float f; } v; v.u = (unsigned)h << 16;
    return v.f;
}

// ------------------------------- zero cnt ------------------------------------
__global__ __launch_bounds__(256)
void zero_cnt(int* __restrict__ cnt, int zt4) {
    int i = blockIdx.x * 256 + threadIdx.x;
    if (i < zt4) reinterpret_cast<int4*>(cnt)[i] = make_int4(0, 0, 0, 0);
}

// ------------- merged: capped CSR fill (dst-partitioned) + prep --------------
__global__ __launch_bounds__(256)
void fill_prep(const int* __restrict__ ei, int* __restrict__ cnt,
               unsigned short* __restrict__ csr_src, int E, int n, int len, int cblk,
               const float* __restrict__ w1a, const float* __restrict__ w1b,
               const float* __restrict__ w2a, const float* __restrict__ w2b,
               unsigned short* __restrict__ o1, unsigned short* __restrict__ o2,
               unsigned short* __restrict__ o3, unsigned short* __restrict__ o4,
               const float* __restrict__ x, unsigned short* __restrict__ xb, int xtotal4) {
    if ((int)blockIdx.x < cblk) {
        const int p = blockIdx.x & (NPART - 1);
        const int s = blockIdx.x / NPART;
        const int chunk = (n + NPART - 1) / NPART;
        const int lo = p * chunk, hi = min(n, lo + chunk);
        const int beg = s * len, end = min(E, beg + len);
        for (int i = beg + (int)threadIdx.x * 4; i < end; i += 256 * 4) {
            int4 d4 = *reinterpret_cast<const int4*>(ei + E + i);
            bool in0 = (d4.x >= lo) & (d4.x < hi);
            bool in1 = (d4.y >= lo) & (d4.y < hi);
            bool in2 = (d4.z >= lo) & (d4.z < hi);
            bool in3 = (d4.w >= lo) & (d4.w < hi);
            if (in0 | in1 | in2 | in3) {
                int4 s4 = *reinterpret_cast<const int4*>(ei + i);
                if (in0) { int q = atomicAdd(&cnt[d4.x], 1); if (q < CAP) csr_src[d4.x * CAP + q] = (unsigned short)s4.x; }
                if (in1) { int q = atomicAdd(&cnt[d4.y], 1); if (q < CAP) csr_src[d4.y * CAP + q] = (unsigned short)s4.y; }
                if (in2) { int q = atomicAdd(&cnt[d4.z], 1); if (q < CAP) csr_src[d4.z * CAP + q] = (unsigned short)s4.z; }
                if (in3) { int q = atomicAdd(&cnt[d4.w], 1); if (q < CAP) csr_src[d4.w * CAP + q] = (unsigned short)s4.w; }
            }
        }
    } else {
        int i = ((int)blockIdx.x - cblk) * 256 + (int)threadIdx.x;
        if (i < 49152) {   // weights: 8192 + 16384 + 16384 + 8192
            const float* w; unsigned short* o; int K, N, idx;
            if (i < 8192)       { w = w1a; o = o1; K = 64;  N = 128; idx = i; }
            else if (i < 24576) { w = w1b; o = o2; K = 128; N = 128; idx = i - 8192; }
            else if (i < 40960) { w = w2a; o = o3; K = 128; N = 128; idx = i - 24576; }
            else                { w = w2b; o = o4; K = 128; N = 64;  idx = i - 40960; }
            int col = idx / K, k = idx % K;
            o[idx] = f2bf(w[k * N + col]);
        } else if (i < 49152 + xtotal4) {
            int j = i - 49152;
            float4 v = reinterpret_cast<const float4*>(x)[j];
            ushort4 o;
            o.x = f2bf(v.x); o.y = f2bf(v.y); o.z = f2bf(v.z); o.w = f2bf(v.w);
            reinterpret_cast<ushort4*>(xb)[j] = o;
        }
    }
}

// ----------------- fused conv: gather + 2-layer MLP via MFMA -----------------
// Block = 256 threads = 4 waves, 64 output rows. Wave w gathers nodes
// [blk*64+w*16, +16) into the LDS A-tile rows it alone consumes in the MFMA
// phase (wave-private -> no barrier; waves desync, overlapping gather loads
// with other waves' MFMAs). Weights staged in LDS (XOR-swizzled,
// conflict-free); Hs wave-private as before. conv1: FIN=64 (lane=ushort
// feat); conv2: FIN=128 (lane=uint=2 feats). LDS: 72KB / 80KB -> 2 blocks/CU.
template<int FIN, int FOUT, bool OUT_BF16>
__global__ __launch_bounds__(256)
void conv_fused(const int* __restrict__ cnt, const unsigned short* __restrict__ cs,
                const void* __restrict__ inp,              // bf16 [*, FIN]
                const unsigned short* __restrict__ waT,    // [128][FIN]
                const float* __restrict__ ba,
                const unsigned short* __restrict__ wbT,    // [FOUT][128]
                const float* __restrict__ bb,
                void* __restrict__ outp, int n) {
    constexpr int KS1 = FIN / 32, CF1 = HIDC / 16;
    constexpr int KS2 = HIDC / 32, CF2 = FOUT / 16;
    __shared__ __align__(16) unsigned short Was[HIDC * FIN];
    __shared__ __align__(16) unsigned short Wbs[FOUT * HIDC];
    __shared__ __align__(16) unsigned short Hs[64 * HIDC];
    __shared__ __align__(16) unsigned short As[64 * FIN];
    const int t = threadIdx.x, wave = t >> 6, lane = t & 63;
    const int lr = lane & 15, lg = lane >> 4;
    const int rowbase = blockIdx.x * 64 + wave * 16;

    // ---- stage weights into LDS, swizzled 16B chunks ----
    constexpr int C1 = FIN / 8;
    for (int i = t; i < HIDC * C1; i += 256) {
        int row = i / C1, kc = i % C1;
        uint4 v = *reinterpret_cast<const uint4*>(waT + row * FIN + kc * 8);
        int bo = ((row * FIN + kc * 8) * 2) ^ ((row & 7) << 4);
        *reinterpret_cast<uint4*>((char*)Was + bo) = v;
    }
    constexpr int C2 = HIDC / 8;
    for (int i = t; i < FOUT * C2; i += 256) {
        int row = i / C2, kc = i % C2;
        uint4 v = *reinterpret_cast<const uint4*>(wbT + row * HIDC + kc * 8);
        int bo = ((row * HIDC + kc * 8) * 2) ^ ((row & 7) << 4);
        *reinterpret_cast<uint4*>((char*)Wbs + bo) = v;
    }
    __syncthreads();

    // ---- gather phase: this wave's 16 nodes -> As rows [wave*16, +16) ----
    for (int i = 0; i < 16; ++i) {
        const int node = rowbase + i;
        const int r = wave * 16 + i;
        if (FIN == 64) {
            const unsigned short* __restrict__ xbp = (const unsigned short*)inp;
            float a0 = 0.f, a1 = 0.f, a2 = 0.f, a3 = 0.f;
            if (node < n) {
                const unsigned short* __restrict__ row = cs + node * CAP;
                const int deg = min(cnt[node], CAP);
                a0 = bf2f(xbp[node * 64 + lane]);
                int e = 0;
                for (; e + 15 < deg; e += 16) {
                    unsigned short u[16];
#pragma unroll
                    for (int j = 0; j < 16; ++j) u[j] = xbp[row[e + j] * 64 + lane];
#pragma unroll
                    for (int j = 0; j < 4; ++j) {
                        a0 += bf2f(u[j]);      a1 += bf2f(u[4 + j]);
                        a2 += bf2f(u[8 + j]);  a3 += bf2f(u[12 + j]);
                    }
                }
                for (; e + 3 < deg; e += 4) {
                    a0 += bf2f(xbp[row[e]     * 64 + lane]);
                    a1 += bf2f(xbp[row[e + 1] * 64 + lane]);
                    a2 += bf2f(xbp[row[e + 2] * 64 + lane]);
                    a3 += bf2f(xbp[row[e + 3] * 64 + lane]);
                }
                for (; e < deg; ++e) a0 += bf2f(xbp[row[e] * 64 + lane]);
            }
            int bo = ((r * FIN + lane) * 2) ^ ((r & 7) << 4);
            *(unsigned short*)((char*)As + bo) = f2bf((a0 + a1) + (a2 + a3));
        } else {
            const unsigned* __restrict__ hp = (const unsigned*)inp;
            float a0 = 0.f, a1 = 0.f, b0 = 0.f, b1 = 0.f;
            if (node < n) {
                const unsigned short* __restrict__ row = cs + node * CAP;
                const int deg = min(cnt[node], CAP);
                unsigned v = hp[node * 64 + lane];
                a0 = bf2f((unsigned short)(v & 0xffffu));
                a1 = bf2f((unsigned short)(v >> 16));
                int e = 0;
                for (; e + 15 < deg; e += 16) {
                    unsigned w[16];
#pragma unroll
                    for (int j = 0; j < 16; ++j) w[j] = hp[row[e + j] * 64 + lane];
#pragma unroll
                    for (int j = 0; j < 8; ++j) {
                        a0 += bf2f((unsigned short)(w[j] & 0xffffu));
                        a1 += bf2f((unsigned short)(w[j] >> 16));
                        b0 += bf2f((unsigned short)(w[8 + j] & 0xffffu));
                        b1 += bf2f((unsigned short)(w[8 + j] >> 16));
                    }
                }
                for (; e + 3 < deg; e += 4) {
                    unsigned w0 = hp[row[e]     * 64 + lane];
                    unsigned w1 = hp[row[e + 1] * 64 + lane];
                    unsigned w2 = hp[row[e + 2] * 64 + lane];
                    unsigned w3 = hp[row[e + 3] * 64 + lane];
                    a0 += bf2f((unsigned short)(w0 & 0xffffu)) + bf2f((unsigned short)(w1 & 0xffffu));
                    a1 += bf2f((unsigned short)(w0 >> 16))     + bf2f((unsigned short)(w1 >> 16));
                    b0 += bf2f((unsigned short)(w2 & 0xffffu)) + bf2f((unsigned short)(w3 & 0xffffu));
                    b1 += bf2f((unsigned short)(w2 >> 16))     + bf2f((unsigned short)(w3 >> 16));
                }
                for (; e < deg; ++e) {
                    unsigned w0 = hp[row[e] * 64 + lane];
                    a0 += bf2f((unsigned short)(w0 & 0xffffu));
                    a1 += bf2f((unsigned short)(w0 >> 16));
                }
            }
            unsigned pk = (unsigned)f2bf(a0 + b0) | ((unsigned)f2bf(a1 + b1) << 16);
            int bo = ((r * FIN + lane * 2) * 2) ^ ((r & 7) << 4);
            *(unsigned*)((char*)As + bo) = pk;
        }
    }
    // no barrier: As rows [wave*16,+16) are wave-private (compiler orders
    // the LDS RAW via lgkmcnt, same as Hs)

    // ---- layer 1: acc1 = A(16xFIN) @ Wa ----
    f32x4 acc1[CF1];
#pragma unroll
    for (int c = 0; c < CF1; ++c) acc1[c] = f32x4{0.f, 0.f, 0.f, 0.f};
#pragma unroll
    for (int ks = 0; ks < KS1; ++ks) {
        const int arow = wave * 16 + lr;
        int ao = ((arow * FIN + ks * 32 + lg * 8) * 2) ^ ((arow & 7) << 4);
        bf16x8 a = *reinterpret_cast<const bf16x8*>((const char*)As + ao);
#pragma unroll
        for (int c = 0; c < CF1; ++c) {
            int bo = (((c * 16 + lr) * FIN + ks * 32 + lg * 8) * 2) ^ ((lr & 7) << 4);
            bf16x8 b = *reinterpret_cast<const bf16x8*>((const char*)Was + bo);
            acc1[c] = __builtin_amdgcn_mfma_f32_16x16x32_bf16(a, b, acc1[c], 0, 0, 0);
        }
    }
    // relu + bias -> Hs (swizzled). D layout: col=lane&15, row=(lane>>4)*4+j.
#pragma unroll
    for (int c = 0; c < CF1; ++c) {
        const int col = c * 16 + lr;
        const float bias = ba[col];
#pragma unroll
        for (int j = 0; j < 4; ++j) {
            const int row = wave * 16 + lg * 4 + j;
            float v = fmaxf(acc1[c][j] + bias, 0.f);
            int bo = (row * (HIDC * 2) + col * 2) ^ ((row & 7) << 4);
            *(unsigned short*)((char*)Hs + bo) = f2bf(v);
        }
    }
    // ---- layer 2 (wave-private Hs rows; no barrier) ----
    f32x4 acc2[CF2];
#pragma unroll
    for (int c = 0; c < CF2; ++c) acc2[c] = f32x4{0.f, 0.f, 0.f, 0.f};
#pragma unroll
    for (int ks = 0; ks < KS2; ++ks) {
        const int row = wave * 16 + lr;
        int ao = (row * (HIDC * 2) + ks * 64 + lg * 16) ^ ((row & 7) << 4);
        bf16x8 a = *reinterpret_cast<const bf16x8*>((const char*)Hs + ao);
#pragma unroll
        for (int c = 0; c < CF2; ++c) {
            int bo = (((c * 16 + lr) * HIDC + ks * 32 + lg * 8) * 2) ^ ((lr & 7) << 4);
            bf16x8 b = *reinterpret_cast<const bf16x8*>((const char*)Wbs + bo);
            acc2[c] = __builtin_amdgcn_mfma_f32_16x16x32_bf16(a, b, acc2[c], 0, 0, 0);
        }
    }
    // ---- epilogue ----
#pragma unroll
    for (int c = 0; c < CF2; ++c) {
        const int col = c * 16 + lr;
        const float bias = bb[col];
#pragma unroll
        for (int j = 0; j < 4; ++j) {
            const int row = rowbase + lg * 4 + j;
            if (row < n) {
                float v = acc2[c][j] + bias;
                if (OUT_BF16)
                    ((unsigned short*)outp)[(long long)row * FOUT + col] = f2bf(v);
                else
                    ((float*)outp)[(long long)row * FOUT + col] = v;
            }
        }
    }
}

extern "C" void kernel_launch(void* const* d_in, const int* in_sizes, int n_in,
                              void* d_out, int out_size, void* d_ws, size_t ws_size,
                              hipStream_t stream) {
    const float* x   = (const float*)d_in[0];
    const int*   ei  = (const int*)d_in[1];
    const float* w1a = (const float*)d_in[2];
    const float* b1a = (const float*)d_in[3];
    const float* w1b = (const float*)d_in[4];
    const float* b1b = (const float*)d_in[5];
    const float* w2a = (const float*)d_in[6];
    const float* b2a = (const float*)d_in[7];
    const float* w2b = (const float*)d_in[8];
    const float* b2b = (const float*)d_in[9];
    float* out = (float*)d_out;

    const int n  = in_sizes[0] / INC;          // 50000 (< 65536 -> ushort ids)
    const int E  = in_sizes[1] / 2;            // 800000
    const int np = ((n + 63) / 64) * 64;       // pad rows to 64-row conv block
    const int n4 = ((n + 3) / 4) * 4;          // cnt zero range (int4)

    // -------- workspace layout --------
    char* ws = (char*)d_ws;
    size_t off = 0;
    auto alloc = [&](size_t bytes) { void* p = ws + off; off += (bytes + 255) & ~size_t(255); return p; };
    unsigned short* xb    = (unsigned short*)alloc((size_t)np * INC  * 2);
    unsigned short* h1    = (unsigned short*)alloc((size_t)np * HIDC * 2);
    unsigned short* w1aT  = (unsigned short*)alloc((size_t)HIDC * INC  * 2);
    unsigned short* w1bT  = (unsigned short*)alloc((size_t)HIDC * HIDC * 2);
    unsigned short* w2aT  = (unsigned short*)alloc((size_t)HIDC * HIDC * 2);
    unsigned short* w2bT  = (unsigned short*)alloc((size_t)OUTC * HIDC * 2);
    int* cnt = (int*)alloc((size_t)n4 * sizeof(int));
    unsigned short* csr_src = (unsigned short*)alloc((size_t)n * CAP * 2);

    const int mblk = np / 64;                  // 64 rows per fused conv block
    const int xt4  = n * INC / 4;
    const int zt4  = n4 / 4;
    const int slen = (((E + NSLICE - 1) / NSLICE) + 3) & ~3;   // slice len, %4==0
    const int cblk = NSLICE * NPART;           // 1024 fill blocks
    const int pblk = (49152 + xt4 + 255) / 256;

    // cnt = 0 (tiny), then merged fill + prep (prep rides under fill's low VALU)
    zero_cnt<<<(zt4 + 255) / 256, 256, 0, stream>>>(cnt, zt4);
    fill_prep<<<cblk + pblk, 256, 0, stream>>>(ei, cnt, csr_src, E, n, slen, cblk,
                                               w1a, w1b, w2a, w2b,
                                               w1aT, w1bT, w2aT, w2bT, x, xb, xt4);

    // -------- conv1 (fused gather+MLP): xb -> h1 --------
    conv_fused<INC, HIDC, true><<<mblk, 256, 0, stream>>>(
        cnt, csr_src, xb, w1aT, b1a, w1bT, b1b, h1, n);

    // -------- conv2 (fused gather+MLP): h1 -> out --------
    conv_fused<HIDC, OUTC, false><<<mblk, 256, 0, stream>>>(
        cnt, csr_src, h1, w2aT, b2a, w2bT, b2b, out, n);
}

// Round 10
// 144.866 us; speedup vs baseline: 1.7088x; 1.7088x over previous
//
#include <hip/hip_runtime.h>

typedef __attribute__((ext_vector_type(8))) short bf16x8;
typedef __attribute__((ext_vector_type(4))) float f32x4;

static constexpr int INC = 64, HIDC = 128, OUTC = 64;
static constexpr int NPART = 8;     // dst partitions == XCDs (bid%8 -> XCD round-robin)
static constexpr int NSLICE = 128;  // edge slices per partition
static constexpr int CAP = 64;      // max degree bucket (Poisson(16): P(>=64)~3e-22)

__device__ __forceinline__ unsigned short f2bf(float f) {
    union { float f; unsigned u; } v; v.f = f;
    unsigned r = v.u + 0x7FFFu + ((v.u >> 16) & 1u);   // round-to-nearest-even
    return (unsigned short)(r >> 16);
}
__device__ __forceinline__ float bf2f(unsigned short h) {
    union { unsigned u; float f; } v; v.u = (unsigned)h << 16;
    return v.f;
}

// ------------------------------- zero cnt ------------------------------------
__global__ __launch_bounds__(256)
void zero_cnt(int* __restrict__ cnt, int zt4) {
    int i = blockIdx.x * 256 + threadIdx.x;
    if (i < zt4) reinterpret_cast<int4*>(cnt)[i] = make_int4(0, 0, 0, 0);
}

// ------------- merged: capped CSR fill (dst-partitioned) + prep --------------
// Blocks [0,cblk): fill. partition p = bid&7 (XCD p under round-robin); only
// edges with dst in p's range processed -> cnt atomics + csr writes XCD-local.
// src int4 loaded lazily. Blocks [cblk,..): prep (weights->bf16T, x->bf16).
__global__ __launch_bounds__(256)
void fill_prep(const int* __restrict__ ei, int* __restrict__ cnt,
               unsigned short* __restrict__ csr_src, int E, int n, int len, int cblk,
               const float* __restrict__ w1a, const float* __restrict__ w1b,
               const float* __restrict__ w2a, const float* __restrict__ w2b,
               unsigned short* __restrict__ o1, unsigned short* __restrict__ o2,
               unsigned short* __restrict__ o3, unsigned short* __restrict__ o4,
               const float* __restrict__ x, unsigned short* __restrict__ xb, int xtotal4) {
    if ((int)blockIdx.x < cblk) {
        const int p = blockIdx.x & (NPART - 1);
        const int s = blockIdx.x / NPART;
        const int chunk = (n + NPART - 1) / NPART;
        const int lo = p * chunk, hi = min(n, lo + chunk);
        const int beg = s * len, end = min(E, beg + len);
        for (int i = beg + (int)threadIdx.x * 4; i < end; i += 256 * 4) {
            int4 d4 = *reinterpret_cast<const int4*>(ei + E + i);
            bool in0 = (d4.x >= lo) & (d4.x < hi);
            bool in1 = (d4.y >= lo) & (d4.y < hi);
            bool in2 = (d4.z >= lo) & (d4.z < hi);
            bool in3 = (d4.w >= lo) & (d4.w < hi);
            if (in0 | in1 | in2 | in3) {
                int4 s4 = *reinterpret_cast<const int4*>(ei + i);
                if (in0) { int q = atomicAdd(&cnt[d4.x], 1); if (q < CAP) csr_src[d4.x * CAP + q] = (unsigned short)s4.x; }
                if (in1) { int q = atomicAdd(&cnt[d4.y], 1); if (q < CAP) csr_src[d4.y * CAP + q] = (unsigned short)s4.y; }
                if (in2) { int q = atomicAdd(&cnt[d4.z], 1); if (q < CAP) csr_src[d4.z * CAP + q] = (unsigned short)s4.z; }
                if (in3) { int q = atomicAdd(&cnt[d4.w], 1); if (q < CAP) csr_src[d4.w * CAP + q] = (unsigned short)s4.w; }
            }
        }
    } else {
        int i = ((int)blockIdx.x - cblk) * 256 + (int)threadIdx.x;
        if (i < 49152) {   // weights: 8192 + 16384 + 16384 + 8192
            const float* w; unsigned short* o; int K, N, idx;
            if (i < 8192)       { w = w1a; o = o1; K = 64;  N = 128; idx = i; }
            else if (i < 24576) { w = w1b; o = o2; K = 128; N = 128; idx = i - 8192; }
            else if (i < 40960) { w = w2a; o = o3; K = 128; N = 128; idx = i - 24576; }
            else                { w = w2b; o = o4; K = 128; N = 64;  idx = i - 40960; }
            int col = idx / K, k = idx % K;
            o[idx] = f2bf(w[k * N + col]);
        } else if (i < 49152 + xtotal4) {
            int j = i - 49152;
            float4 v = reinterpret_cast<const float4*>(x)[j];
            ushort4 o;
            o.x = f2bf(v.x); o.y = f2bf(v.y); o.z = f2bf(v.z); o.w = f2bf(v.w);
            reinterpret_cast<ushort4*>(xb)[j] = o;
        }
    }
}

// --- gather1: bf16 x [n][64] -> bf16 aggr1. Wave/node; two 32-lane groups ---
// fetch DIFFERENT edges per instruction (2 rows in flight per load); lane sl
// covers feats [2sl,2sl+1] as one uint. shfl_xor(32) merges groups at end.
__global__ __launch_bounds__(256)
void gather1(const int* __restrict__ cnt, const unsigned short* __restrict__ cs,
             const unsigned* __restrict__ xbu, unsigned* __restrict__ outu, int n) {
    const int wid  = (blockIdx.x * 256 + threadIdx.x) >> 6;
    const int lane = threadIdx.x & 63;
    if (wid >= n) return;
    const int grp = lane >> 5, sl = lane & 31;
    const unsigned short* __restrict__ row = cs + wid * CAP;
    const int deg = min(cnt[wid], CAP);
    float a0 = 0.f, a1 = 0.f, b0 = 0.f, b1 = 0.f;
    if (grp == 0) {   // self term ((1+eps)*x, eps=0) in group 0 only
        unsigned v = xbu[wid * 32 + sl];
        a0 = bf2f((unsigned short)(v & 0xffffu));
        a1 = bf2f((unsigned short)(v >> 16));
    }
    int e = 0;
    for (; e + 15 < deg; e += 16) {     // 8 pairs: 8 rows in flight per group
        unsigned u[8];
#pragma unroll
        for (int j = 0; j < 8; ++j) u[j] = xbu[row[e + 2 * j + grp] * 32 + sl];
#pragma unroll
        for (int j = 0; j < 4; ++j) {
            a0 += bf2f((unsigned short)(u[j] & 0xffffu));
            a1 += bf2f((unsigned short)(u[j] >> 16));
            b0 += bf2f((unsigned short)(u[4 + j] & 0xffffu));
            b1 += bf2f((unsigned short)(u[4 + j] >> 16));
        }
    }
    for (; e + 1 < deg; e += 2) {
        unsigned v = xbu[row[e + grp] * 32 + sl];
        a0 += bf2f((unsigned short)(v & 0xffffu));
        a1 += bf2f((unsigned short)(v >> 16));
    }
    if (e < deg && grp == 0) {          // odd tail
        unsigned v = xbu[row[e] * 32 + sl];
        a0 += bf2f((unsigned short)(v & 0xffffu));
        a1 += bf2f((unsigned short)(v >> 16));
    }
    a0 += b0; a1 += b1;
    a0 += __shfl_xor(a0, 32);
    a1 += __shfl_xor(a1, 32);
    if (grp == 0)
        outu[wid * 32 + sl] = (unsigned)f2bf(a0) | ((unsigned)f2bf(a1) << 16);
}

// --- gather2: bf16 h1 [n][128] -> bf16 aggr2. Same split; lane = uint2 = 4f --
__global__ __launch_bounds__(256)
void gather2(const int* __restrict__ cnt, const unsigned short* __restrict__ cs,
             const uint2* __restrict__ h2, uint2* __restrict__ out2, int n) {
    const int wid  = (blockIdx.x * 256 + threadIdx.x) >> 6;
    const int lane = threadIdx.x & 63;
    if (wid >= n) return;
    const int grp = lane >> 5, sl = lane & 31;
    const unsigned short* __restrict__ row = cs + wid * CAP;
    const int deg = min(cnt[wid], CAP);
    float a0 = 0.f, a1 = 0.f, a2 = 0.f, a3 = 0.f;
    float b0 = 0.f, b1 = 0.f, b2 = 0.f, b3 = 0.f;
    if (grp == 0) {   // self term
        uint2 v = h2[wid * 32 + sl];
        a0 = bf2f((unsigned short)(v.x & 0xffffu));
        a1 = bf2f((unsigned short)(v.x >> 16));
        a2 = bf2f((unsigned short)(v.y & 0xffffu));
        a3 = bf2f((unsigned short)(v.y >> 16));
    }
    int e = 0;
    for (; e + 15 < deg; e += 16) {     // 8 pairs: 8 rows in flight per group
        uint2 u[8];
#pragma unroll
        for (int j = 0; j < 8; ++j) u[j] = h2[row[e + 2 * j + grp] * 32 + sl];
#pragma unroll
        for (int j = 0; j < 4; ++j) {
            a0 += bf2f((unsigned short)(u[j].x & 0xffffu));
            a1 += bf2f((unsigned short)(u[j].x >> 16));
            a2 += bf2f((unsigned short)(u[j].y & 0xffffu));
            a3 += bf2f((unsigned short)(u[j].y >> 16));
            b0 += bf2f((unsigned short)(u[4 + j].x & 0xffffu));
            b1 += bf2f((unsigned short)(u[4 + j].x >> 16));
            b2 += bf2f((unsigned short)(u[4 + j].y & 0xffffu));
            b3 += bf2f((unsigned short)(u[4 + j].y >> 16));
        }
    }
    for (; e + 1 < deg; e += 2) {
        uint2 v = h2[row[e + grp] * 32 + sl];
        a0 += bf2f((unsigned short)(v.x & 0xffffu));
        a1 += bf2f((unsigned short)(v.x >> 16));
        a2 += bf2f((unsigned short)(v.y & 0xffffu));
        a3 += bf2f((unsigned short)(v.y >> 16));
    }
    if (e < deg && grp == 0) {          // odd tail
        uint2 v = h2[row[e] * 32 + sl];
        a0 += bf2f((unsigned short)(v.x & 0xffffu));
        a1 += bf2f((unsigned short)(v.x >> 16));
        a2 += bf2f((unsigned short)(v.y & 0xffffu));
        a3 += bf2f((unsigned short)(v.y >> 16));
    }
    a0 += b0; a1 += b1; a2 += b2; a3 += b3;
    a0 += __shfl_xor(a0, 32);
    a1 += __shfl_xor(a1, 32);
    a2 += __shfl_xor(a2, 32);
    a3 += __shfl_xor(a3, 32);
    if (grp == 0) {
        uint2 o;
        o.x = (unsigned)f2bf(a0) | ((unsigned)f2bf(a1) << 16);
        o.y = (unsigned)f2bf(a2) | ((unsigned)f2bf(a3) << 16);
        out2[wid * 32 + sl] = o;
    }
}

// --------------------- fused 2-layer MLP via bf16 MFMA -----------------------
// Block = 256 threads = 4 waves; 128 rows/block, each wave runs two 16-row
// tiles (weight staging amortized 2x). Weights in LDS (XOR-swizzled,
// conflict-free ds_read_b128); H in LDS per-wave private (no barrier between
// layers). LDS = 64KB max.
template<int FIN, int FOUT, bool OUT_BF16>
__global__ __launch_bounds__(256)
void mlp_mfma(const unsigned short* __restrict__ A,
              const unsigned short* __restrict__ waT,   // [128][FIN]
              const float* __restrict__ ba,
              const unsigned short* __restrict__ wbT,   // [FOUT][128]
              const float* __restrict__ bb,
              void* __restrict__ outp, int n) {
    constexpr int KS1 = FIN / 32, CF1 = HIDC / 16;
    constexpr int KS2 = HIDC / 32, CF2 = FOUT / 16;
    __shared__ __align__(16) unsigned short Was[HIDC * FIN];
    __shared__ __align__(16) unsigned short Wbs[FOUT * HIDC];
    __shared__ __align__(16) unsigned short Hs[64 * HIDC];
    const int t = threadIdx.x, wave = t >> 6, lane = t & 63;
    const int lr = lane & 15, lg = lane >> 4;

    // ---- stage weights into LDS, swizzled 16B chunks ----
    constexpr int C1 = FIN / 8;
    for (int i = t; i < HIDC * C1; i += 256) {
        int row = i / C1, kc = i % C1;
        uint4 v = *reinterpret_cast<const uint4*>(waT + row * FIN + kc * 8);
        int bo = ((row * FIN + kc * 8) * 2) ^ ((row & 7) << 4);
        *reinterpret_cast<uint4*>((char*)Was + bo) = v;
    }
    constexpr int C2 = HIDC / 8;
    for (int i = t; i < FOUT * C2; i += 256) {
        int row = i / C2, kc = i % C2;
        uint4 v = *reinterpret_cast<const uint4*>(wbT + row * HIDC + kc * 8);
        int bo = ((row * HIDC + kc * 8) * 2) ^ ((row & 7) << 4);
        *reinterpret_cast<uint4*>((char*)Wbs + bo) = v;
    }
    __syncthreads();

    for (int tt = 0; tt < 2; ++tt) {
        const int rowbase = blockIdx.x * 128 + tt * 64 + wave * 16;

        // ---- layer 1: acc1 = A(16xFIN) @ Wa ----
        f32x4 acc1[CF1];
#pragma unroll
        for (int c = 0; c < CF1; ++c) acc1[c] = f32x4{0.f, 0.f, 0.f, 0.f};
#pragma unroll
        for (int ks = 0; ks < KS1; ++ks) {
            bf16x8 a = *reinterpret_cast<const bf16x8*>(
                A + (long long)(rowbase + lr) * FIN + ks * 32 + lg * 8);
#pragma unroll
            for (int c = 0; c < CF1; ++c) {
                int bo = (((c * 16 + lr) * FIN + ks * 32 + lg * 8) * 2) ^ ((lr & 7) << 4);
                bf16x8 b = *reinterpret_cast<const bf16x8*>((const char*)Was + bo);
                acc1[c] = __builtin_amdgcn_mfma_f32_16x16x32_bf16(a, b, acc1[c], 0, 0, 0);
            }
        }
        // relu + bias -> Hs (swizzled). D layout: col=lane&15, row=(lane>>4)*4+j.
#pragma unroll
        for (int c = 0; c < CF1; ++c) {
            const int col = c * 16 + lr;
            const float bias = ba[col];
#pragma unroll
            for (int j = 0; j < 4; ++j) {
                const int row = wave * 16 + lg * 4 + j;
                float v = fmaxf(acc1[c][j] + bias, 0.f);
                int bo = (row * (HIDC * 2) + col * 2) ^ ((row & 7) << 4);
                *(unsigned short*)((char*)Hs + bo) = f2bf(v);
            }
        }
        // ---- layer 2 (wave-private Hs rows; no barrier) ----
        f32x4 acc2[CF2];
#pragma unroll
        for (int c = 0; c < CF2; ++c) acc2[c] = f32x4{0.f, 0.f, 0.f, 0.f};
#pragma unroll
        for (int ks = 0; ks < KS2; ++ks) {
            const int row = wave * 16 + lr;
            int ao = (row * (HIDC * 2) + ks * 64 + lg * 16) ^ ((row & 7) << 4);
            bf16x8 a = *reinterpret_cast<const bf16x8*>((const char*)Hs + ao);
#pragma unroll
            for (int c = 0; c < CF2; ++c) {
                int bo = (((c * 16 + lr) * HIDC + ks * 32 + lg * 8) * 2) ^ ((lr & 7) << 4);
                bf16x8 b = *reinterpret_cast<const bf16x8*>((const char*)Wbs + bo);
                acc2[c] = __builtin_amdgcn_mfma_f32_16x16x32_bf16(a, b, acc2[c], 0, 0, 0);
            }
        }
        // ---- epilogue ----
#pragma unroll
        for (int c = 0; c < CF2; ++c) {
            const int col = c * 16 + lr;
            const float bias = bb[col];
#pragma unroll
            for (int j = 0; j < 4; ++j) {
                const int row = rowbase + lg * 4 + j;
                if (row < n) {
                    float v = acc2[c][j] + bias;
                    if (OUT_BF16)
                        ((unsigned short*)outp)[(long long)row * FOUT + col] = f2bf(v);
                    else
                        ((float*)outp)[(long long)row * FOUT + col] = v;
                }
            }
        }
    }
}

extern "C" void kernel_launch(void* const* d_in, const int* in_sizes, int n_in,
                              void* d_out, int out_size, void* d_ws, size_t ws_size,
                              hipStream_t stream) {
    const float* x   = (const float*)d_in[0];
    const int*   ei  = (const int*)d_in[1];
    const float* w1a = (const float*)d_in[2];
    const float* b1a = (const float*)d_in[3];
    const float* w1b = (const float*)d_in[4];
    const float* b1b = (const float*)d_in[5];
    const float* w2a = (const float*)d_in[6];
    const float* b2a = (const float*)d_in[7];
    const float* w2b = (const float*)d_in[8];
    const float* b2b = (const float*)d_in[9];
    float* out = (float*)d_out;

    const int n  = in_sizes[0] / INC;          // 50000 (< 65536 -> ushort ids)
    const int E  = in_sizes[1] / 2;            // 800000
    const int np = ((n + 127) / 128) * 128;    // pad rows to 128-row MFMA block
    const int n4 = ((n + 3) / 4) * 4;          // cnt zero range (int4)

    // -------- workspace layout --------
    char* ws = (char*)d_ws;
    size_t off = 0;
    auto alloc = [&](size_t bytes) { void* p = ws + off; off += (bytes + 255) & ~size_t(255); return p; };
    unsigned short* xb    = (unsigned short*)alloc((size_t)np * INC  * 2);
    unsigned short* aggr1 = (unsigned short*)alloc((size_t)np * INC  * 2);
    unsigned short* h1    = (unsigned short*)alloc((size_t)np * HIDC * 2);
    unsigned short* aggr2 = (unsigned short*)alloc((size_t)np * HIDC * 2);
    unsigned short* w1aT  = (unsigned short*)alloc((size_t)HIDC * INC  * 2);
    unsigned short* w1bT  = (unsigned short*)alloc((size_t)HIDC * HIDC * 2);
    unsigned short* w2aT  = (unsigned short*)alloc((size_t)HIDC * HIDC * 2);
    unsigned short* w2bT  = (unsigned short*)alloc((size_t)OUTC * HIDC * 2);
    int* cnt = (int*)alloc((size_t)n4 * sizeof(int));
    unsigned short* csr_src = (unsigned short*)alloc((size_t)n * CAP * 2);

    const int gblk = (n * 64 + 255) / 256;     // wave per node
    const int mblk = np / 128;                 // 128 rows per MFMA block
    const int xt4  = n * INC / 4;
    const int zt4  = n4 / 4;
    const int slen = (((E + NSLICE - 1) / NSLICE) + 3) & ~3;   // slice len, %4==0
    const int cblk = NSLICE * NPART;           // 1024 fill blocks
    const int pblk = (49152 + xt4 + 255) / 256;

    // cnt = 0 (tiny), then merged fill + prep (prep rides under fill's low VALU)
    zero_cnt<<<(zt4 + 255) / 256, 256, 0, stream>>>(cnt, zt4);
    fill_prep<<<cblk + pblk, 256, 0, stream>>>(ei, cnt, csr_src, E, n, slen, cblk,
                                               w1a, w1b, w2a, w2b,
                                               w1aT, w1bT, w2aT, w2bT, x, xb, xt4);

    // -------- conv1 --------
    gather1<<<gblk, 256, 0, stream>>>(cnt, csr_src, (const unsigned*)xb, (unsigned*)aggr1, n);
    mlp_mfma<INC, HIDC, true><<<mblk, 256, 0, stream>>>(aggr1, w1aT, b1a, w1bT, b1b, h1, n);

    // -------- conv2 --------
    gather2<<<gblk, 256, 0, stream>>>(cnt, csr_src, (const uint2*)h1, (uint2*)aggr2, n);
    mlp_mfma<HIDC, OUTC, false><<<mblk, 256, 0, stream>>>(aggr2, w2aT, b2a, w2bT, b2b, out, n);
}

// Round 11
// 136.900 us; speedup vs baseline: 1.8083x; 1.0582x over previous
//
#include <hip/hip_runtime.h>

typedef __attribute__((ext_vector_type(8))) short bf16x8;
typedef __attribute__((ext_vector_type(4))) float f32x4;
typedef __attribute__((ext_vector_type(4))) int int4v;

static constexpr int INC = 64, HIDC = 128, OUTC = 64;
static constexpr int NPART = 8;     // dst partitions == XCDs (bid%8 -> XCD round-robin)
static constexpr int NSLICE = 128;  // edge slices per partition
static constexpr int CAP = 64;      // max degree bucket (Poisson(16): P(>=64)~3e-22)

__device__ __forceinline__ unsigned short f2bf(float f) {
    union { float f; unsigned u; } v; v.f = f;
    unsigned r = v.u + 0x7FFFu + ((v.u >> 16) & 1u);   // round-to-nearest-even
    return (unsigned short)(r >> 16);
}
__device__ __forceinline__ float bf2f(unsigned short h) {
    union { unsigned u; float f; } v; v.u = (unsigned)h << 16;
    return v.f;
}

// ------------------------------- zero cnt ------------------------------------
__global__ __launch_bounds__(256)
void zero_cnt(int* __restrict__ cnt, int zt4) {
    int i = blockIdx.x * 256 + threadIdx.x;
    if (i < zt4) reinterpret_cast<int4v*>(cnt)[i] = int4v{0, 0, 0, 0};
}

// ------------- merged: capped CSR fill (dst-partitioned) + prep --------------
// Blocks [0,cblk): fill. partition p = bid&7 (XCD p under round-robin); only
// edges with dst in p's range processed -> cnt atomics + csr writes XCD-local.
// Edge stream read NON-TEMPORALLY so it does not evict the dirty csr_src
// lines from L2 between a node's ~16 touches (the 25 MB partial-writeback
// amplification seen in round 10's counters). src int4 loaded lazily.
// Blocks [cblk,..): prep (weights->bf16T, x->bf16).
__global__ __launch_bounds__(256)
void fill_prep(const int* __restrict__ ei, int* __restrict__ cnt,
               unsigned short* __restrict__ csr_src, int E, int n, int len, int cblk,
               const float* __restrict__ w1a, const float* __restrict__ w1b,
               const float* __restrict__ w2a, const float* __restrict__ w2b,
               unsigned short* __restrict__ o1, unsigned short* __restrict__ o2,
               unsigned short* __restrict__ o3, unsigned short* __restrict__ o4,
               const float* __restrict__ x, unsigned short* __restrict__ xb, int xtotal4) {
    if ((int)blockIdx.x < cblk) {
        const int p = blockIdx.x & (NPART - 1);
        const int s = blockIdx.x / NPART;
        const int chunk = (n + NPART - 1) / NPART;
        const int lo = p * chunk, hi = min(n, lo + chunk);
        const int beg = s * len, end = min(E, beg + len);
        for (int i = beg + (int)threadIdx.x * 4; i < end; i += 256 * 4) {
            int4v d4 = __builtin_nontemporal_load(
                reinterpret_cast<const int4v*>(ei + E + i));
            bool in0 = (d4.x >= lo) & (d4.x < hi);
            bool in1 = (d4.y >= lo) & (d4.y < hi);
            bool in2 = (d4.z >= lo) & (d4.z < hi);
            bool in3 = (d4.w >= lo) & (d4.w < hi);
            if (in0 | in1 | in2 | in3) {
                int4v s4 = __builtin_nontemporal_load(
                    reinterpret_cast<const int4v*>(ei + i));
                if (in0) { int q = atomicAdd(&cnt[d4.x], 1); if (q < CAP) csr_src[d4.x * CAP + q] = (unsigned short)s4.x; }
                if (in1) { int q = atomicAdd(&cnt[d4.y], 1); if (q < CAP) csr_src[d4.y * CAP + q] = (unsigned short)s4.y; }
                if (in2) { int q = atomicAdd(&cnt[d4.z], 1); if (q < CAP) csr_src[d4.z * CAP + q] = (unsigned short)s4.z; }
                if (in3) { int q = atomicAdd(&cnt[d4.w], 1); if (q < CAP) csr_src[d4.w * CAP + q] = (unsigned short)s4.w; }
            }
        }
    } else {
        int i = ((int)blockIdx.x - cblk) * 256 + (int)threadIdx.x;
        if (i < 49152) {   // weights: 8192 + 16384 + 16384 + 8192
            const float* w; unsigned short* o; int K, N, idx;
            if (i < 8192)       { w = w1a; o = o1; K = 64;  N = 128; idx = i; }
            else if (i < 24576) { w = w1b; o = o2; K = 128; N = 128; idx = i - 8192; }
            else if (i < 40960) { w = w2a; o = o3; K = 128; N = 128; idx = i - 24576; }
            else                { w = w2b; o = o4; K = 128; N = 64;  idx = i - 40960; }
            int col = idx / K, k = idx % K;
            o[idx] = f2bf(w[k * N + col]);
        } else if (i < 49152 + xtotal4) {
            int j = i - 49152;
            float4 v = reinterpret_cast<const float4*>(x)[j];
            ushort4 o;
            o.x = f2bf(v.x); o.y = f2bf(v.y); o.z = f2bf(v.z); o.w = f2bf(v.w);
            reinterpret_cast<ushort4*>(xb)[j] = o;
        }
    }
}

// ----- gather1: bf16 x [n][64] -> bf16 aggr1 (wave/node, lane=feat, x16) -----
__global__ __launch_bounds__(256)
void gather1(const int* __restrict__ cnt, const unsigned short* __restrict__ cs,
             const unsigned short* __restrict__ xb, unsigned short* __restrict__ out, int n) {
    const int wid  = (blockIdx.x * 256 + threadIdx.x) >> 6;
    const int lane = threadIdx.x & 63;
    if (wid >= n) return;
    const unsigned short* __restrict__ row = cs + wid * CAP;
    const int deg = min(cnt[wid], CAP);
    float a0 = bf2f(xb[wid * 64 + lane]), a1 = 0.f, a2 = 0.f, a3 = 0.f;
    int e = 0;
    for (; e + 15 < deg; e += 16) {
        unsigned short u[16];
#pragma unroll
        for (int j = 0; j < 16; ++j) u[j] = xb[row[e + j] * 64 + lane];
#pragma unroll
        for (int j = 0; j < 4; ++j) {
            a0 += bf2f(u[j]);      a1 += bf2f(u[4 + j]);
            a2 += bf2f(u[8 + j]);  a3 += bf2f(u[12 + j]);
        }
    }
    for (; e + 3 < deg; e += 4) {
        a0 += bf2f(xb[row[e]     * 64 + lane]);
        a1 += bf2f(xb[row[e + 1] * 64 + lane]);
        a2 += bf2f(xb[row[e + 2] * 64 + lane]);
        a3 += bf2f(xb[row[e + 3] * 64 + lane]);
    }
    for (; e < deg; ++e) a0 += bf2f(xb[row[e] * 64 + lane]);
    out[wid * 64 + lane] = f2bf((a0 + a1) + (a2 + a3));
}

// ---- gather2: bf16 h1 [n][128] -> bf16 aggr2 (lane = uint = 2 feats, x16) ---
__global__ __launch_bounds__(256)
void gather2(const int* __restrict__ cnt, const unsigned short* __restrict__ cs,
             const unsigned* __restrict__ h, unsigned* __restrict__ out, int n) {
    const int wid  = (blockIdx.x * 256 + threadIdx.x) >> 6;
    const int lane = threadIdx.x & 63;
    if (wid >= n) return;
    const unsigned short* __restrict__ row = cs + wid * CAP;
    const int deg = min(cnt[wid], CAP);
    unsigned v = h[wid * 64 + lane];
    float a0 = bf2f((unsigned short)(v & 0xffffu));
    float a1 = bf2f((unsigned short)(v >> 16));
    float b0 = 0.f, b1 = 0.f;
    int e = 0;
    for (; e + 15 < deg; e += 16) {
        unsigned w[16];
#pragma unroll
        for (int j = 0; j < 16; ++j) w[j] = h[row[e + j] * 64 + lane];
#pragma unroll
        for (int j = 0; j < 8; ++j) {
            a0 += bf2f((unsigned short)(w[j] & 0xffffu));
            a1 += bf2f((unsigned short)(w[j] >> 16));
            b0 += bf2f((unsigned short)(w[8 + j] & 0xffffu));
            b1 += bf2f((unsigned short)(w[8 + j] >> 16));
        }
    }
    for (; e + 3 < deg; e += 4) {
        unsigned w0 = h[row[e]     * 64 + lane];
        unsigned w1 = h[row[e + 1] * 64 + lane];
        unsigned w2 = h[row[e + 2] * 64 + lane];
        unsigned w3 = h[row[e + 3] * 64 + lane];
        a0 += bf2f((unsigned short)(w0 & 0xffffu)) + bf2f((unsigned short)(w1 & 0xffffu));
        a1 += bf2f((unsigned short)(w0 >> 16))     + bf2f((unsigned short)(w1 >> 16));
        b0 += bf2f((unsigned short)(w2 & 0xffffu)) + bf2f((unsigned short)(w3 & 0xffffu));
        b1 += bf2f((unsigned short)(w2 >> 16))     + bf2f((unsigned short)(w3 >> 16));
    }
    for (; e < deg; ++e) {
        unsigned w0 = h[row[e] * 64 + lane];
        a0 += bf2f((unsigned short)(w0 & 0xffffu));
        a1 += bf2f((unsigned short)(w0 >> 16));
    }
    out[wid * 64 + lane] = (unsigned)f2bf(a0 + b0) | ((unsigned)f2bf(a1 + b1) << 16);
}

// --------------------- fused 2-layer MLP via bf16 MFMA -----------------------
// Block = 256 threads = 4 waves; 128 rows/block, each wave runs two 16-row
// tiles (weight staging amortized 2x). Weights in LDS (XOR-swizzled,
// conflict-free ds_read_b128); H in LDS per-wave private (no barrier between
// layers). LDS = 64KB max.
template<int FIN, int FOUT, bool OUT_BF16>
__global__ __launch_bounds__(256)
void mlp_mfma(const unsigned short* __restrict__ A,
              const unsigned short* __restrict__ waT,   // [128][FIN]
              const float* __restrict__ ba,
              const unsigned short* __restrict__ wbT,   // [FOUT][128]
              const float* __restrict__ bb,
              void* __restrict__ outp, int n) {
    constexpr int KS1 = FIN / 32, CF1 = HIDC / 16;
    constexpr int KS2 = HIDC / 32, CF2 = FOUT / 16;
    __shared__ __align__(16) unsigned short Was[HIDC * FIN];
    __shared__ __align__(16) unsigned short Wbs[FOUT * HIDC];
    __shared__ __align__(16) unsigned short Hs[64 * HIDC];
    const int t = threadIdx.x, wave = t >> 6, lane = t & 63;
    const int lr = lane & 15, lg = lane >> 4;

    // ---- stage weights into LDS, swizzled 16B chunks ----
    constexpr int C1 = FIN / 8;
    for (int i = t; i < HIDC * C1; i += 256) {
        int row = i / C1, kc = i % C1;
        uint4 v = *reinterpret_cast<const uint4*>(waT + row * FIN + kc * 8);
        int bo = ((row * FIN + kc * 8) * 2) ^ ((row & 7) << 4);
        *reinterpret_cast<uint4*>((char*)Was + bo) = v;
    }
    constexpr int C2 = HIDC / 8;
    for (int i = t; i < FOUT * C2; i += 256) {
        int row = i / C2, kc = i % C2;
        uint4 v = *reinterpret_cast<const uint4*>(wbT + row * HIDC + kc * 8);
        int bo = ((row * HIDC + kc * 8) * 2) ^ ((row & 7) << 4);
        *reinterpret_cast<uint4*>((char*)Wbs + bo) = v;
    }
    __syncthreads();

    for (int tt = 0; tt < 2; ++tt) {
        const int rowbase = blockIdx.x * 128 + tt * 64 + wave * 16;

        // ---- layer 1: acc1 = A(16xFIN) @ Wa ----
        f32x4 acc1[CF1];
#pragma unroll
        for (int c = 0; c < CF1; ++c) acc1[c] = f32x4{0.f, 0.f, 0.f, 0.f};
#pragma unroll
        for (int ks = 0; ks < KS1; ++ks) {
            bf16x8 a = *reinterpret_cast<const bf16x8*>(
                A + (long long)(rowbase + lr) * FIN + ks * 32 + lg * 8);
#pragma unroll
            for (int c = 0; c < CF1; ++c) {
                int bo = (((c * 16 + lr) * FIN + ks * 32 + lg * 8) * 2) ^ ((lr & 7) << 4);
                bf16x8 b = *reinterpret_cast<const bf16x8*>((const char*)Was + bo);
                acc1[c] = __builtin_amdgcn_mfma_f32_16x16x32_bf16(a, b, acc1[c], 0, 0, 0);
            }
        }
        // relu + bias -> Hs (swizzled). D layout: col=lane&15, row=(lane>>4)*4+j.
#pragma unroll
        for (int c = 0; c < CF1; ++c) {
            const int col = c * 16 + lr;
            const float bias = ba[col];
#pragma unroll
            for (int j = 0; j < 4; ++j) {
                const int row = wave * 16 + lg * 4 + j;
                float v = fmaxf(acc1[c][j] + bias, 0.f);
                int bo = (row * (HIDC * 2) + col * 2) ^ ((row & 7) << 4);
                *(unsigned short*)((char*)Hs + bo) = f2bf(v);
            }
        }
        // ---- layer 2 (wave-private Hs rows; no barrier) ----
        f32x4 acc2[CF2];
#pragma unroll
        for (int c = 0; c < CF2; ++c) acc2[c] = f32x4{0.f, 0.f, 0.f, 0.f};
#pragma unroll
        for (int ks = 0; ks < KS2; ++ks) {
            const int row = wave * 16 + lr;
            int ao = (row * (HIDC * 2) + ks * 64 + lg * 16) ^ ((row & 7) << 4);
            bf16x8 a = *reinterpret_cast<const bf16x8*>((const char*)Hs + ao);
#pragma unroll
            for (int c = 0; c < CF2; ++c) {
                int bo = (((c * 16 + lr) * HIDC + ks * 32 + lg * 8) * 2) ^ ((lr & 7) << 4);
                bf16x8 b = *reinterpret_cast<const bf16x8*>((const char*)Wbs + bo);
                acc2[c] = __builtin_amdgcn_mfma_f32_16x16x32_bf16(a, b, acc2[c], 0, 0, 0);
            }
        }
        // ---- epilogue ----
#pragma unroll
        for (int c = 0; c < CF2; ++c) {
            const int col = c * 16 + lr;
            const float bias = bb[col];
#pragma unroll
            for (int j = 0; j < 4; ++j) {
                const int row = rowbase + lg * 4 + j;
                if (row < n) {
                    float v = acc2[c][j] + bias;
                    if (OUT_BF16)
                        ((unsigned short*)outp)[(long long)row * FOUT + col] = f2bf(v);
                    else
                        ((float*)outp)[(long long)row * FOUT + col] = v;
                }
            }
        }
    }
}

extern "C" void kernel_launch(void* const* d_in, const int* in_sizes, int n_in,
                              void* d_out, int out_size, void* d_ws, size_t ws_size,
                              hipStream_t stream) {
    const float* x   = (const float*)d_in[0];
    const int*   ei  = (const int*)d_in[1];
    const float* w1a = (const float*)d_in[2];
    const float* b1a = (const float*)d_in[3];
    const float* w1b = (const float*)d_in[4];
    const float* b1b = (const float*)d_in[5];
    const float* w2a = (const float*)d_in[6];
    const float* b2a = (const float*)d_in[7];
    const float* w2b = (const float*)d_in[8];
    const float* b2b = (const float*)d_in[9];
    float* out = (float*)d_out;

    const int n  = in_sizes[0] / INC;          // 50000 (< 65536 -> ushort ids)
    const int E  = in_sizes[1] / 2;            // 800000
    const int np = ((n + 127) / 128) * 128;    // pad rows to 128-row MFMA block
    const int n4 = ((n + 3) / 4) * 4;          // cnt zero range (int4)

    // -------- workspace layout --------
    char* ws = (char*)d_ws;
    size_t off = 0;
    auto alloc = [&](size_t bytes) { void* p = ws + off; off += (bytes + 255) & ~size_t(255); return p; };
    unsigned short* xb    = (unsigned short*)alloc((size_t)np * INC  * 2);
    unsigned short* aggr1 = (unsigned short*)alloc((size_t)np * INC  * 2);
    unsigned short* h1    = (unsigned short*)alloc((size_t)np * HIDC * 2);
    unsigned short* aggr2 = (unsigned short*)alloc((size_t)np * HIDC * 2);
    unsigned short* w1aT  = (unsigned short*)alloc((size_t)HIDC * INC  * 2);
    unsigned short* w1bT  = (unsigned short*)alloc((size_t)HIDC * HIDC * 2);
    unsigned short* w2aT  = (unsigned short*)alloc((size_t)HIDC * HIDC * 2);
    unsigned short* w2bT  = (unsigned short*)alloc((size_t)OUTC * HIDC * 2);
    int* cnt = (int*)alloc((size_t)n4 * sizeof(int));
    unsigned short* csr_src = (unsigned short*)alloc((size_t)n * CAP * 2);

    const int gblk = (n * 64 + 255) / 256;     // wave per node
    const int mblk = np / 128;                 // 128 rows per MFMA block
    const int xt4  = n * INC / 4;
    const int zt4  = n4 / 4;
    const int slen = (((E + NSLICE - 1) / NSLICE) + 3) & ~3;   // slice len, %4==0
    const int cblk = NSLICE * NPART;           // 1024 fill blocks
    const int pblk = (49152 + xt4 + 255) / 256;

    // cnt = 0 (tiny), then merged fill + prep (prep rides under fill's low VALU)
    zero_cnt<<<(zt4 + 255) / 256, 256, 0, stream>>>(cnt, zt4);
    fill_prep<<<cblk + pblk, 256, 0, stream>>>(ei, cnt, csr_src, E, n, slen, cblk,
                                               w1a, w1b, w2a, w2b,
                                               w1aT, w1bT, w2aT, w2bT, x, xb, xt4);

    // -------- conv1 --------
    gather1<<<gblk, 256, 0, stream>>>(cnt, csr_src, xb, aggr1, n);
    mlp_mfma<INC, HIDC, true><<<mblk, 256, 0, stream>>>(aggr1, w1aT, b1a, w1bT, b1b, h1, n);

    // -------- conv2 --------
    gather2<<<gblk, 256, 0, stream>>>(cnt, csr_src, (const unsigned*)h1, (unsigned*)aggr2, n);
    mlp_mfma<HIDC, OUTC, false><<<mblk, 256, 0, stream>>>(aggr2, w2aT, b2a, w2bT, b2b, out, n);
}